// Round 8
// baseline (220.724 us; speedup 1.0000x reference)
//
#include <hip/hip_runtime.h>

// CapsuleLayer dynamic routing, MI355X fp32.
// x: [B=64, N=2048, I=8], W: [J=32, N=2048, D=16, I=8], out v: [B=64, J=32, D=16]
//
// b_t = u_hat . (v_0+...+v_{t-1})  =>  u_hat (256 MB) never materialized;
// each phase recomputes it in registers from x + W (L2-resident via XCD
// swizzle; FETCH ~21 MB/phase measured R4/R5). R8 (R6/R7 coop fusion was a
// measured dead end: 737us/dispatch): split pipeline with
//   - NL_BATCH=2: two n's per barrier round -> 16 barriers/phase, not 32
//   - unsafeAtomicAdd accumulation into A[B][J][D] (128 KB) -> kills the
//     16.8 MB partial write + 16.8 MB reduce read per phase; reduce becomes
//     a ~2us squash. HW global_atomic_add_f32; 128 adds/address contention.

#define BB_ 64
#define NN_ 2048
#define II_ 8
#define JJ_ 32
#define DD_ 16
#define NCHUNKS 128
#define CHUNK 16       /* n's per block */
#define BG 8           /* b's per block */
#define NBG (BB_ / BG) /* 8 */
#define EPS_ 1e-7f
#define OUT_ELEMS (BB_ * JJ_ * DD_) /* 32768 */

typedef __attribute__((ext_vector_type(2))) float v2f;

// DPP helpers (VALU-pipe cross-lane). CTRL must be an immediate.
template <int CTRL>
__device__ __forceinline__ float dpp_add(float v) {
  const int s = __builtin_amdgcn_update_dpp(
      0, __builtin_bit_cast(int, v), CTRL, 0xf, 0xf, true);
  return v + __builtin_bit_cast(float, s);
}
#define DPP_QP_XOR1 0xB1      /* quad_perm [1,0,3,2]  : lane ^ 1 */
#define DPP_QP_XOR2 0x4E      /* quad_perm [2,3,0,1]  : lane ^ 2 */
#define DPP_HALF_MIRROR 0x141 /* mirror within 8      : lane ^ 7 */
#define DPP_ROR8 0x128        /* row_ror:8 (16-lane)  : lane ^ 8 */

// 256 threads = (j = tid>>3) x (p = tid&7); thread owns output cap j, dims
// d in {2p,2p+1}, for 8 b's. blockIdx = bg*NCHUNKS + chunk so blockIdx%8 ==
// chunk%8 -> all 8 blocks sharing a W chunk-slab (256 KB) land on one XCD
// (16 slabs x 256 KB = 4 MB = one L2).
template <int PHASE>
__global__ __launch_bounds__(256, 4) void caps_phase(
    const float* __restrict__ x, const float* __restrict__ W,
    const float* __restrict__ V, float* __restrict__ A) {
  const int tid = threadIdx.x;
  const int j = tid >> 3;
  const int p = tid & 7;
  const int chunk = blockIdx.x & (NCHUNKS - 1);
  const int bg = blockIdx.x >> 7;
  const int b0 = bg * BG;
  const int n0 = chunk * CHUNK;

  __shared__ float lmat[2][BG][JJ_];
  __shared__ float cmat[2][BG][JJ_];

  // V fragment: V[b0+b][j][2p..2p+1] for 8 b's.
  float v0r[BG], v1r[BG];
  if (PHASE > 0) {
#pragma unroll
    for (int b = 0; b < BG; ++b) {
      const float2 vv =
          *(const float2*)&V[((size_t)(b0 + b) * JJ_ + j) * DD_ + 2 * p];
      v0r[b] = vv.x;
      v1r[b] = vv.y;
    }
  }

  v2f s[BG];
#pragma unroll
  for (int b = 0; b < BG; ++b) s[b] = (v2f)(0.f);

  // W[j][n][d][i]: thread reads 16 consecutive floats at j*262144 + n*128 + p*16.
  const float* wp = W + (size_t)j * (NN_ * DD_ * II_) +
                    (size_t)n0 * (DD_ * II_) + (size_t)p * 16;

  for (int nl = 0; nl < CHUNK; nl += 2) {
    v2f u[2][BG];
#pragma unroll
    for (int q = 0; q < 2; ++q) {
      const int n = n0 + nl + q;
      const float4* wq = (const float4*)(wp + (size_t)(nl + q) * (DD_ * II_));
      const float4 wc0 = wq[0], wc1 = wq[1], wc2 = wq[2], wc3 = wq[3];
      // Pack W pairs {W[d0][i], W[d1][i]} -> v_pk_fma operands.
      const v2f wk0 = {wc0.x, wc2.x}, wk1 = {wc0.y, wc2.y};
      const v2f wk2 = {wc0.z, wc2.z}, wk3 = {wc0.w, wc2.w};
      const v2f wk4 = {wc1.x, wc3.x}, wk5 = {wc1.y, wc3.y};
      const v2f wk6 = {wc1.z, wc3.z}, wk7 = {wc1.w, wc3.w};
#pragma unroll
      for (int b = 0; b < BG; ++b) {
        // Wave-uniform x row (b, n uniform): scalar-load path, no LDS.
        const float4* __restrict__ xr =
            (const float4*)(x + ((size_t)(b0 + b) * NN_ + n) * II_);
        const float4 xa = xr[0];
        const float4 xb = xr[1];
        v2f acc = wk0 * xa.x;
        acc += wk1 * xa.y;
        acc += wk2 * xa.z;
        acc += wk3 * xa.w;
        acc += wk4 * xb.x;
        acc += wk5 * xb.y;
        acc += wk6 * xb.z;
        acc += wk7 * xb.w;
        u[q][b] = acc;
      }
    }

    if (PHASE == 0) {
      // softmax(0) over J is uniform -> plain sum (scale at store).
#pragma unroll
      for (int b = 0; b < BG; ++b) s[b] += u[0][b] + u[1][b];
    } else {
      // logits: 2-elem partial per lane, xor butterfly over the 8 p-lanes
      // (all lanes end with the full sum; p==0 stores).
#pragma unroll
      for (int q = 0; q < 2; ++q)
#pragma unroll
        for (int b = 0; b < BG; ++b) {
          float lp = u[q][b].x * v0r[b] + u[q][b].y * v1r[b];
          lp = dpp_add<DPP_QP_XOR1>(lp);
          lp = dpp_add<DPP_QP_XOR2>(lp);
          lp = dpp_add<DPP_HALF_MIRROR>(lp);
          if (p == 0) lmat[q][b][j] = lp;
        }
      __syncthreads();
      // softmax over j (32) x 8 b x 2 q = 512 entries, 2 per thread.
      // |logit| <= ~1.5: exp safe without max subtraction (validated R2-R7).
      {
        const int jj = tid & 31;
        const int bb = tid >> 5;
#pragma unroll
        for (int q = 0; q < 2; ++q) {
          const float e0 = __expf(lmat[q][bb][jj]);
          float m0 = e0;
          m0 = dpp_add<DPP_QP_XOR1>(m0);
          m0 = dpp_add<DPP_QP_XOR2>(m0);
          m0 = dpp_add<DPP_HALF_MIRROR>(m0);
          m0 = dpp_add<DPP_ROR8>(m0);
          m0 += __shfl_xor(m0, 16);
          cmat[q][bb][jj] = e0 * __builtin_amdgcn_rcpf(m0);
        }
      }
      __syncthreads();
#pragma unroll
      for (int q = 0; q < 2; ++q)
#pragma unroll
        for (int b = 0; b < BG; ++b) {
          const float c = cmat[q][b][j];  // broadcast (all p-lanes same addr)
          s[b] += u[q][b] * c;            // one v_pk_fma
        }
      // no 3rd sync: next round's lmat writes are gated by the cmat barrier.
    }
  }

  // Accumulate into A[B][J][D] via HW fp32 atomics (128 adds/address total).
  const float scale = (PHASE == 0) ? (1.0f / 32.0f) : 1.0f;
#pragma unroll
  for (int b = 0; b < BG; ++b) {
    float* a = &A[((size_t)(b0 + b) * JJ_ + j) * DD_ + 2 * p];
    unsafeAtomicAdd(a, s[b].x * scale);
    unsafeAtomicAdd(a + 1, s[b].y * scale);
  }
}

__global__ __launch_bounds__(128) void caps_zero(float* __restrict__ A) {
  A[blockIdx.x * 128 + threadIdx.x] = 0.f;
}

// Squash A -> V/out; re-zero A for the next phase. MODE 0: V=v; 1: V+=v;
// 2: out=v (no re-zero needed). 256 blocks x 128 threads (all CUs).
template <int MODE>
__global__ __launch_bounds__(128) void caps_squash(float* __restrict__ A,
                                                   float* __restrict__ V,
                                                   float* __restrict__ out) {
  const int t = blockIdx.x * 128 + threadIdx.x;  // [0, B*J*D)
  const float s = A[t];
  if (MODE < 2) A[t] = 0.f;
  // sum of squares over d (16 consecutive lanes = one (b,j))
  float ss = s * s;
  ss += __shfl_xor(ss, 1);
  ss += __shfl_xor(ss, 2);
  ss += __shfl_xor(ss, 4);
  ss += __shfl_xor(ss, 8);
  const float v = s / sqrtf(ss + EPS_);
  if (MODE == 0)
    V[t] = v;
  else if (MODE == 1)
    V[t] += v;
  else
    out[t] = v;
}

extern "C" void kernel_launch(void* const* d_in, const int* in_sizes, int n_in,
                              void* d_out, int out_size, void* d_ws,
                              size_t ws_size, hipStream_t stream) {
  const float* x = (const float*)d_in[0];
  const float* W = (const float*)d_in[1];
  float* out = (float*)d_out;
  float* A = (float*)d_ws;    // 128 KB accumulator
  float* V = A + OUT_ELEMS;   // 128 KB cumulative v

  const dim3 kgrid(NBG * NCHUNKS);   // 1024 blocks x 256 threads
  const dim3 rgrid(OUT_ELEMS / 128); // 256 blocks x 128 threads

  caps_zero<<<rgrid, 128, 0, stream>>>(A);
  caps_phase<0><<<kgrid, 256, 0, stream>>>(x, W, nullptr, A);
  caps_squash<0><<<rgrid, 128, 0, stream>>>(A, V, out);
  caps_phase<1><<<kgrid, 256, 0, stream>>>(x, W, V, A);
  caps_squash<1><<<rgrid, 128, 0, stream>>>(A, V, out);
  caps_phase<2><<<kgrid, 256, 0, stream>>>(x, W, V, A);
  caps_squash<2><<<rgrid, 128, 0, stream>>>(A, V, out);
}